// Round 4
// baseline (88533.105 us; speedup 1.0000x reference)
//
#include <hip/hip_runtime.h>
#include <math.h>

#define B_ 128
#define S_ 256
#define I_ 512
#define H_ 1024
#define O_ 512
#define T_ 128
#define KB 32

__device__ __forceinline__ float sigmoidf_(float x) {
    return 1.0f / (1.0f + expf(-x));
}

// ---------------------------------------------------------------------------
// LSTM cell step, weights via wave-uniform (scalar) loads.
// Grid 256 blocks x 256 threads. Block: units j0..j0+3 (16 gate rows), 128 batch.
// Thread (tb=tid&127, tj=tid>>7): batch tb, units {j0+2tj, j0+2tj+1}, 4 gates each.
// Per k: 1 ds_read_b32 (a) + 8 FMA with wave-uniform w (SGPR path; no W in LDS).
// Optional x-phase (ntx tiles, K_x = ntx*KB) then h-phase (32 tiles, K=1024).
// ---------------------------------------------------------------------------
__global__ __launch_bounds__(256) void lstm_cell2(
    const float* __restrict__ A1, int lda1,   // x-phase input [128 x ntx*KB] (row stride lda1)
    const float* __restrict__ Wx,             // [4H x ntx*KB]
    int ntx,                                  // x-phase tile count (0 => skip)
    const float* __restrict__ hin,            // [128 x 1024]
    const float* __restrict__ Wh,             // [4H x 1024]
    const float* __restrict__ bsum,           // [4H]
    float* __restrict__ hout,                 // [128 x 1024]
    float* __restrict__ c)                    // [128 x 1024] in/out
{
    __shared__ float As[2][B_][33];   // a tile [buf][b][k]; pad 33 -> read bank (b+k)%32, 2-way free
    __shared__ float ht[B_][5];
    __shared__ float ct[B_][5];

    const int tid = threadIdx.x;
    const int tb  = tid & 127;
    // tid>>7 is wave-uniform (waves are 64-aligned); force scalar so W addrs scalarize.
    const int tjs = __builtin_amdgcn_readfirstlane(tid >> 7);   // 0..1
    const int j0  = blockIdx.x * 4;
    const int ldwx = ntx * KB;
    const int nt = ntx + H_ / KB;

    // 8 wave-uniform W row bases: r = u*4+g -> row g*H + j0 + 2*tjs + u
    const float* wxb[8];
    const float* whb[8];
#pragma unroll
    for (int r = 0; r < 8; ++r) {
        const int row = (r & 3) * H_ + j0 + 2 * tjs + (r >> 2);
        wxb[r] = Wx + (size_t)row * ldwx;
        whb[r] = Wh + (size_t)row * H_;
    }

    float acc[2][4];
#pragma unroll
    for (int u = 0; u < 2; ++u)
#pragma unroll
        for (int g = 0; g < 4; ++g)
            acc[u][g] = bsum[g * H_ + j0 + 2 * tjs + u];

    float4 pa[4];
    auto load_tile = [&](int t) {
        const float* A; int lda; int k0;
        if (t < ntx) { A = A1;  lda = lda1; k0 = t * KB; }
        else         { A = hin; lda = H_;  k0 = (t - ntx) * KB; }
#pragma unroll
        for (int rep = 0; rep < 4; ++rep) {
            const int flat = tid + rep * 256;           // 0..1023
            pa[rep] = *reinterpret_cast<const float4*>(
                A + (size_t)(flat >> 3) * lda + k0 + ((flat & 7) << 2));
        }
    };
    auto write_tile = [&](int p) {
#pragma unroll
        for (int rep = 0; rep < 4; ++rep) {
            const int flat = tid + rep * 256;
            const int b = flat >> 3;
            const int q = (flat & 7) << 2;
            As[p][b][q + 0] = pa[rep].x;
            As[p][b][q + 1] = pa[rep].y;
            As[p][b][q + 2] = pa[rep].z;
            As[p][b][q + 3] = pa[rep].w;
        }
    };

    load_tile(0);
    write_tile(0);
    __syncthreads();

    int p = 0;
    for (int t = 0; t < nt; ++t) {
        if (t + 1 < nt) load_tile(t + 1);
        // select phase weight bases (wave-uniform)
        const bool xph = (t < ntx);
        const float* wb[8];
#pragma unroll
        for (int r = 0; r < 8; ++r) wb[r] = xph ? wxb[r] : whb[r];
        const int kO = xph ? t * KB : (t - ntx) * KB;
#pragma unroll
        for (int kq = 0; kq < 8; ++kq) {
            float4 wv[8];
#pragma unroll
            for (int r = 0; r < 8; ++r)
                wv[r] = *reinterpret_cast<const float4*>(wb[r] + kO + kq * 4);
#pragma unroll
            for (int kk = 0; kk < 4; ++kk) {
                const float a = As[p][tb][kq * 4 + kk];
#pragma unroll
                for (int u = 0; u < 2; ++u)
#pragma unroll
                    for (int g = 0; g < 4; ++g)
                        acc[u][g] = fmaf(a, ((const float*)&wv[u * 4 + g])[kk], acc[u][g]);
            }
        }
        if (t + 1 < nt) write_tile(p ^ 1);
        __syncthreads();
        p ^= 1;
    }

    // ---- epilogue: LDS exchange, coalesced float4 c/h writes ----
    if (tid < 128) {
        const float4 cv = *reinterpret_cast<const float4*>(&c[(size_t)tid * H_ + j0]);
        ct[tid][0] = cv.x; ct[tid][1] = cv.y; ct[tid][2] = cv.z; ct[tid][3] = cv.w;
    }
    __syncthreads();
#pragma unroll
    for (int u = 0; u < 2; ++u) {
        const int s = tjs * 2 + u;
        const float iv = sigmoidf_(acc[u][0]);
        const float fv = sigmoidf_(acc[u][1]);
        const float gv = tanhf(acc[u][2]);
        const float ov = sigmoidf_(acc[u][3]);
        const float cn = fv * ct[tb][s] + iv * gv;
        ct[tb][s] = cn;
        ht[tb][s] = ov * tanhf(cn);
    }
    __syncthreads();
    if (tid < 128) {
        float4 co, ho;
        co.x = ct[tid][0]; co.y = ct[tid][1]; co.z = ct[tid][2]; co.w = ct[tid][3];
        ho.x = ht[tid][0]; ho.y = ht[tid][1]; ho.z = ht[tid][2]; ho.w = ht[tid][3];
        *reinterpret_cast<float4*>(&c[(size_t)tid * H_ + j0])    = co;
        *reinterpret_cast<float4*>(&hout[(size_t)tid * H_ + j0]) = ho;
    }
}

// ---------------------------------------------------------------------------
// Chunked projection: y[row] = h[row,:] @ Wp^T + bp for row in [0, nrows).
// row -> (tloc = row>>7, b = row&127); writes out_base[b*T*O + tloc*O + o].
// Grid (nrows/64)*64 blocks x 256 threads; block = 64 rows x 8 outs.
// ---------------------------------------------------------------------------
__global__ __launch_bounds__(256) void proj2(
    const float* __restrict__ hrows,  // [nrows x 1024]
    const float* __restrict__ Wp,     // [512 x 1024]
    const float* __restrict__ bp,     // [512]
    float* __restrict__ out_base,     // d_out + t0*O_
    float* __restrict__ yfb)          // optional feedback (fallback tier, nrows==128)
{
    __shared__ float Hs[2][64][33];
    __shared__ float Ps[2][KB][8];
    __shared__ float yt[64][9];

    const int tid = threadIdx.x;
    const int tb  = tid & 63;
    const int th  = tid >> 6;          // 0..3
    const int rb  = blockIdx.x >> 6;
    const int o0  = (blockIdx.x & 63) * 8;
    const float* h = hrows + (size_t)rb * 64 * H_;

    const int pr = tid & 7;
    const int pq = (tid >> 3) & 7;

    float acc0 = 0.f, acc1 = 0.f;
    float4 pa[2];
    float4 pw;

    auto load_tile = [&](int t) {
        const int k0 = t * KB;
#pragma unroll
        for (int rep = 0; rep < 2; ++rep) {
            const int flat = tid + rep * 256;           // 0..511
            pa[rep] = *reinterpret_cast<const float4*>(
                h + (size_t)(flat >> 3) * H_ + k0 + ((flat & 7) << 2));
        }
        if (tid < 64) {
            pw = *reinterpret_cast<const float4*>(
                Wp + (size_t)(o0 + pr) * H_ + k0 + (pq << 2));
        }
    };
    auto write_tile = [&](int p) {
#pragma unroll
        for (int rep = 0; rep < 2; ++rep) {
            const int flat = tid + rep * 256;
            const int bb = flat >> 3;
            const int q = (flat & 7) << 2;
            Hs[p][bb][q + 0] = pa[rep].x;
            Hs[p][bb][q + 1] = pa[rep].y;
            Hs[p][bb][q + 2] = pa[rep].z;
            Hs[p][bb][q + 3] = pa[rep].w;
        }
        if (tid < 64) {
            const int kk = pq << 2;
            Ps[p][kk + 0][pr] = pw.x;
            Ps[p][kk + 1][pr] = pw.y;
            Ps[p][kk + 2][pr] = pw.z;
            Ps[p][kk + 3][pr] = pw.w;
        }
    };

    load_tile(0);
    write_tile(0);
    __syncthreads();

    int p = 0;
    for (int t = 0; t < H_ / KB; ++t) {
        if (t + 1 < H_ / KB) load_tile(t + 1);
#pragma unroll
        for (int k = 0; k < KB; ++k) {
            const float a = Hs[p][tb][k];
            const float2 w = *reinterpret_cast<const float2*>(&Ps[p][k][th * 2]);
            acc0 = fmaf(a, w.x, acc0);
            acc1 = fmaf(a, w.y, acc1);
        }
        if (t + 1 < H_ / KB) write_tile(p ^ 1);
        __syncthreads();
        p ^= 1;
    }

    yt[tb][th * 2 + 0] = acc0 + bp[o0 + th * 2 + 0];
    yt[tb][th * 2 + 1] = acc1 + bp[o0 + th * 2 + 1];
    __syncthreads();
    if (tid < 128) {
        const int bb   = tid >> 1;
        const int half = (tid & 1) * 4;
        float4 v;
        v.x = yt[bb][half + 0]; v.y = yt[bb][half + 1];
        v.z = yt[bb][half + 2]; v.w = yt[bb][half + 3];
        const int glob = rb * 64 + bb;
        const int tloc = glob >> 7;
        const int b    = glob & 127;
        *reinterpret_cast<float4*>(
            &out_base[(size_t)b * (T_ * O_) + (size_t)tloc * O_ + o0 + half]) = v;
        if (yfb)
            *reinterpret_cast<float4*>(&yfb[(size_t)b * O_ + o0 + half]) = v;
    }
}

// ---------------------------------------------------------------------------
// Weff = Whh_d + Wih_d @ Wp   ([4096x1024] += [4096x512] @ [512x1024]); runs once.
// Grid 1024 blocks (64 r-tiles x 16 m-tiles) x 256 threads; thread 4x4.
// ---------------------------------------------------------------------------
__global__ __launch_bounds__(256) void weff_kernel(
    const float* __restrict__ Wihd,
    const float* __restrict__ Wp,
    const float* __restrict__ Whhd,
    float* __restrict__ Weff)
{
    __shared__ float Asx[KB][68];
    __shared__ float Bs[KB][68];
    const int tid = threadIdx.x;
    const int bx = blockIdx.x & 63;
    const int by = blockIdx.x >> 6;
    const int r0 = bx * 64, m0 = by * 64;
    const int tr = tid >> 4, tm = tid & 15;
    float acc[4][4] = {};

    for (int k0 = 0; k0 < I_; k0 += KB) {
        __syncthreads();
#pragma unroll
        for (int rep = 0; rep < 2; ++rep) {
            const int flat = tid + rep * 256;          // 0..511
            const int r = flat >> 3, q = flat & 7;
            const float4 v = *reinterpret_cast<const float4*>(
                Wihd + (size_t)(r0 + r) * I_ + k0 + q * 4);
            Asx[q * 4 + 0][r] = v.x; Asx[q * 4 + 1][r] = v.y;
            Asx[q * 4 + 2][r] = v.z; Asx[q * 4 + 3][r] = v.w;
        }
#pragma unroll
        for (int rep = 0; rep < 2; ++rep) {
            const int flat = tid + rep * 256;
            const int k = flat >> 4, mq = flat & 15;
            const float4 v = *reinterpret_cast<const float4*>(
                Wp + (size_t)(k0 + k) * H_ + m0 + mq * 4);
            *reinterpret_cast<float4*>(&Bs[k][mq * 4]) = v;
        }
        __syncthreads();
#pragma unroll
        for (int k = 0; k < KB; ++k) {
            const float4 a4 = *reinterpret_cast<const float4*>(&Asx[k][tr * 4]);
            const float4 b4 = *reinterpret_cast<const float4*>(&Bs[k][tm * 4]);
            const float av[4] = {a4.x, a4.y, a4.z, a4.w};
            const float bv[4] = {b4.x, b4.y, b4.z, b4.w};
#pragma unroll
            for (int i = 0; i < 4; ++i)
#pragma unroll
                for (int j = 0; j < 4; ++j)
                    acc[i][j] = fmaf(av[i], bv[j], acc[i][j]);
        }
    }
#pragma unroll
    for (int i = 0; i < 4; ++i) {
        const size_t row = r0 + tr * 4 + i;
        const float4 w = *reinterpret_cast<const float4*>(
            Whhd + row * H_ + m0 + tm * 4);
        float4 o;
        o.x = acc[i][0] + w.x; o.y = acc[i][1] + w.y;
        o.z = acc[i][2] + w.z; o.w = acc[i][3] + w.w;
        *reinterpret_cast<float4*>(&Weff[row * H_ + m0 + tm * 4]) = o;
    }
}

// be = bih_e + bhh_e ; bd = bih_d + bhh_d ; beff = bd + Wih_d @ bp
__global__ void prep_kernel(
    const float* __restrict__ bi_e, const float* __restrict__ bh_e,
    const float* __restrict__ bi_d, const float* __restrict__ bh_d,
    const float* __restrict__ Wihd, const float* __restrict__ bp,
    float* __restrict__ be, float* __restrict__ bd, float* __restrict__ beff)
{
    const int n = blockIdx.x * 256 + threadIdx.x;
    if (n >= 4 * H_) return;
    be[n] = bi_e[n] + bh_e[n];
    const float bdv = bi_d[n] + bh_d[n];
    bd[n] = bdv;
    float s = 0.f;
    const float4* wr = reinterpret_cast<const float4*>(Wihd + (size_t)n * I_);
    const float4* bv = reinterpret_cast<const float4*>(bp);
#pragma unroll 4
    for (int q = 0; q < I_ / 4; ++q) {
        const float4 w = wr[q];
        const float4 b = bv[q];
        s += w.x * b.x + w.y * b.y + w.z * b.z + w.w * b.w;
    }
    beff[n] = bdv + s;
}

extern "C" void kernel_launch(void* const* d_in, const int* in_sizes, int n_in,
                              void* d_out, int out_size, void* d_ws, size_t ws_size,
                              hipStream_t stream) {
    const float* x     = (const float*)d_in[0];
    // d_in[1] = tgt_len (compile-time T_ = 128)
    const float* Wih_e = (const float*)d_in[2];
    const float* Whh_e = (const float*)d_in[3];
    const float* bih_e = (const float*)d_in[4];
    const float* bhh_e = (const float*)d_in[5];
    const float* Wih_d = (const float*)d_in[6];
    const float* Whh_d = (const float*)d_in[7];
    const float* bih_d = (const float*)d_in[8];
    const float* bhh_d = (const float*)d_in[9];
    const float* Wp    = (const float*)d_in[10];
    const float* bp    = (const float*)d_in[11];
    float* out = (float*)d_out;
    float* ws  = (float*)d_ws;

    // ws layout (floats); zeroed prefix first:
    // [c 131072][henc0 131072][yfb 65536][henc1 131072][be 4096][bd 4096][beff 4096]
    // [Weff 4194304][hist NCH*131072]
    float* c     = ws;
    float* henc0 = ws + 131072;
    float* yfb   = ws + 262144;
    float* henc1 = ws + 327680;
    float* be    = ws + 458752;
    float* bd    = ws + 462848;
    float* beff  = ws + 466944;
    float* Weff  = ws + 471040;
    float* hist  = ws + 4665344;

    // tier by workspace size
    const size_t need128 = (size_t)(4665344 + 128 * 131072) * 4;
    const size_t need16  = (size_t)(4665344 + 16 * 131072) * 4;
    int NCH;
    if      (ws_size >= need128) NCH = 128;
    else if (ws_size >= need16)  NCH = 16;
    else                         NCH = 0;   // fallback: unfused decoder

    hipMemsetAsync(ws, 0, (size_t)327680 * sizeof(float), stream);
    prep_kernel<<<16, 256, 0, stream>>>(bih_e, bhh_e, bih_d, bhh_d, Wih_d, bp,
                                        be, bd, beff);
    if (NCH > 0)
        weff_kernel<<<1024, 256, 0, stream>>>(Wih_d, Wp, Whh_d, Weff);

    float* hin  = henc0;
    float* hout = henc1;

    // ---- encoder: x-phase (16 tiles) + h-phase ----
    for (int t = 0; t < S_; ++t) {
        lstm_cell2<<<256, 256, 0, stream>>>(
            x + (size_t)t * I_, S_ * I_, Wih_e, 16, hin, Whh_e, be, hout, c);
        float* tmp = hin; hin = hout; hout = tmp;
    }

    if (NCH > 0) {
        // ---- fused decoder: h-only recurrence; batched projection per chunk ----
        const float* prev = hin;
        for (int t = 0; t < T_; ++t) {
            float* hdst = hist + (size_t)(t % NCH) * (B_ * H_);
            lstm_cell2<<<256, 256, 0, stream>>>(
                nullptr, 0, nullptr, 0, prev,
                (t == 0) ? Whh_d : Weff,
                (t == 0) ? bd    : beff,
                hdst, c);
            prev = hdst;
            if ((t + 1) % NCH == 0) {
                const int t0 = t + 1 - NCH;
                proj2<<<(NCH * 128 / 64) * 64, 256, 0, stream>>>(
                    hist, Wp, bp, out + (size_t)t0 * O_, nullptr);
            }
        }
    } else {
        // ---- fallback decoder: y-feedback through x-phase, per-step proj ----
        for (int t = 0; t < T_; ++t) {
            lstm_cell2<<<256, 256, 0, stream>>>(
                yfb, O_, Wih_d, 16, hin, Whh_d, bd, hout, c);
            float* tmp = hin; hin = hout; hout = tmp;
            proj2<<<(128 / 64) * 64, 256, 0, stream>>>(
                hin, Wp, bp, out + (size_t)t * O_, yfb);
        }
    }
}

// Round 6
// 30397.775 us; speedup vs baseline: 2.9125x; 2.9125x over previous
//
#include <hip/hip_runtime.h>
#include <math.h>

#define B_ 128
#define S_ 256
#define I_ 512
#define H_ 1024
#define O_ 512
#define T_ 128
#define LDA 36            // padded bf16 elems per 32-k LDS row (72B: 8B-aligned, bank-clean)

typedef __attribute__((ext_vector_type(8)))  short s16x8;
typedef __attribute__((ext_vector_type(16))) float f32x16;

__device__ __forceinline__ ushort f2bf(float x) {
    union { float f; uint u; } v; v.f = x;
    return (ushort)((v.u + 0x7FFFu + ((v.u >> 16) & 1u)) >> 16);
}
__device__ __forceinline__ float bf2f(ushort h) {
    union { uint u; float f; } v; v.u = ((uint)h) << 16; return v.f;
}

// split fp32x4 -> bf16 hi/lo planes (3-term compensated product; lo well above
// bf16 min-normal -> no subnormal-flush hazard, unlike f16 split)
__device__ __forceinline__ void cvt4(float4 v, uint2& hi, uint2& lo) {
    union { ushort h[4]; uint2 u; } H, L;
    ushort a;
    a = f2bf(v.x); H.h[0] = a; L.h[0] = f2bf(v.x - bf2f(a));
    a = f2bf(v.y); H.h[1] = a; L.h[1] = f2bf(v.y - bf2f(a));
    a = f2bf(v.z); H.h[2] = a; L.h[2] = f2bf(v.z - bf2f(a));
    a = f2bf(v.w); H.h[3] = a; L.h[3] = f2bf(v.w - bf2f(a));
    hi = H.u; lo = L.u;
}

__device__ __forceinline__ s16x8 rdfrag(const ushort* p) {
    union { s16x8 v; uint2 u[2]; } r;
    r.u[0] = *(const uint2*)(p);
    r.u[1] = *(const uint2*)(p + 4);
    return r.v;
}

// ---------------------------------------------------------------------------
// LSTM cell, bf16x3 MFMA (32x32x16). Weight rows permuted: rho = unit*4+gate
// so each lane's C-reg quad = the 4 gates of one unit (C/D row map m74/m101).
// Grid 256 = 64 row-blocks (16 units) x 4 batch-blocks (32 batch). 128 thr.
// XCD swizzle: the 4 batch-duplicates of a row-block share blockIdx%8 -> same
// XCD -> per-XCD weight slice ~3.2MB stays L2-resident across all steps.
// ---------------------------------------------------------------------------
__global__ __launch_bounds__(128) void cell_mfma(
    const float* __restrict__ xsrc, int ldx,          // [128 x ntx*32] fp32
    const ushort* __restrict__ WXh, const ushort* __restrict__ WXl,
    const float* __restrict__ WX32, int ntx,
    const float* __restrict__ hin,                    // [128 x 1024] fp32
    const ushort* __restrict__ WHh, const ushort* __restrict__ WHl,
    const float* __restrict__ WH32,
    const float* __restrict__ bperm,                  // [4096] permuted bias sum
    float* __restrict__ hout,                         // [128 x 1024]
    float* __restrict__ cT)                           // [1024 x 128] transposed
{
    __shared__ __align__(16) ushort As[2][2][64][LDA];   // [buf][hi/lo][row][k]
    __shared__ __align__(16) ushort Bs[2][2][32][LDA];
    __shared__ float Lh[32][20];

    const int tid  = threadIdx.x;
    const int lane = tid & 63;
    const int wr   = tid >> 6;            // wave: 0,1
    const int bid  = blockIdx.x;
    const int rb   = (bid & 7) + 8 * (bid >> 5);   // row-block 0..63 (XCD = bid&7)
    const int bb   = (bid >> 3) & 3;               // batch-block 0..3
    const int j0   = rb * 16;             // first unit
    const int rho0 = rb * 64;             // first permuted gate-row
    const int b0   = bb * 32;             // first batch
    const int nt   = ntx + 32;

    uint4  pA[4];
    float4 pAf[4];
    float4 pB[2];
    bool   curAfly = false;

    auto load_tile = [&](int t) {
        const bool xph = (t < ntx);
        const int  k0  = (xph ? t : t - ntx) * 32;
        const ushort* Ph = xph ? WXh : WHh;
        const ushort* Pl = xph ? WXl : WHl;
        const int  K   = xph ? ntx * 32 : H_;
        curAfly = (Ph == nullptr);
        if (!curAfly) {
#pragma unroll
            for (int rep = 0; rep < 2; ++rep) {
                const int flat = tid + rep * 128;      // 0..255
                const int r = flat >> 2, c = flat & 3;
                const size_t off = (size_t)(rho0 + r) * K + k0 + c * 8;
                pA[rep * 2 + 0] = *(const uint4*)(Ph + off);
                pA[rep * 2 + 1] = *(const uint4*)(Pl + off);
            }
        } else {
            const float* W32 = xph ? WX32 : WH32;
#pragma unroll
            for (int rep = 0; rep < 4; ++rep) {
                const int flat = tid + rep * 128;      // 0..511
                const int r = flat >> 3, q = flat & 7;
                const int rho = rho0 + r;
                const size_t srow = (size_t)(rho & 3) * H_ + (rho >> 2);
                pAf[rep] = *(const float4*)(W32 + srow * K + k0 + q * 4);
            }
        }
        const float* Bsrc = xph ? xsrc : hin;
        const int    ldb  = xph ? ldx : H_;
#pragma unroll
        for (int rep = 0; rep < 2; ++rep) {
            const int flat = tid + rep * 128;          // 0..255
            const int r = flat >> 3, q = flat & 7;
            pB[rep] = *(const float4*)(Bsrc + (size_t)(b0 + r) * ldb + k0 + q * 4);
        }
    };

    auto write_tile = [&](int p) {
        if (!curAfly) {
#pragma unroll
            for (int rep = 0; rep < 2; ++rep) {
                const int flat = tid + rep * 128;
                const int r = flat >> 2, c = flat & 3;
                const uint2* h2 = (const uint2*)&pA[rep * 2 + 0];
                const uint2* l2 = (const uint2*)&pA[rep * 2 + 1];
                *(uint2*)&As[p][0][r][c * 8]     = h2[0];
                *(uint2*)&As[p][0][r][c * 8 + 4] = h2[1];
                *(uint2*)&As[p][1][r][c * 8]     = l2[0];
                *(uint2*)&As[p][1][r][c * 8 + 4] = l2[1];
            }
        } else {
#pragma unroll
            for (int rep = 0; rep < 4; ++rep) {
                const int flat = tid + rep * 128;
                const int r = flat >> 3, q = flat & 7;
                uint2 hi, lo; cvt4(pAf[rep], hi, lo);
                *(uint2*)&As[p][0][r][q * 4] = hi;
                *(uint2*)&As[p][1][r][q * 4] = lo;
            }
        }
#pragma unroll
        for (int rep = 0; rep < 2; ++rep) {
            const int flat = tid + rep * 128;
            const int r = flat >> 3, q = flat & 7;
            uint2 hi, lo; cvt4(pB[rep], hi, lo);
            *(uint2*)&Bs[p][0][r][q * 4] = hi;
            *(uint2*)&Bs[p][1][r][q * 4] = lo;
        }
    };

    f32x16 acc;
#pragma unroll
    for (int i = 0; i < 16; ++i) acc[i] = 0.0f;

    const int arow = wr * 32 + (lane & 31);
    const int brow = lane & 31;
    const int koff = (lane >> 5) * 8;

    load_tile(0);
    write_tile(0);
    __syncthreads();

    int p = 0;
    for (int t = 0; t < nt; ++t) {
        if (t + 1 < nt) load_tile(t + 1);
#pragma unroll
        for (int ks = 0; ks < 2; ++ks) {
            const s16x8 ah = rdfrag(&As[p][0][arow][ks * 16 + koff]);
            const s16x8 al = rdfrag(&As[p][1][arow][ks * 16 + koff]);
            const s16x8 bh = rdfrag(&Bs[p][0][brow][ks * 16 + koff]);
            const s16x8 bl = rdfrag(&Bs[p][1][brow][ks * 16 + koff]);
            acc = __builtin_amdgcn_mfma_f32_32x32x16_bf16(ah, bh, acc, 0, 0, 0);
            acc = __builtin_amdgcn_mfma_f32_32x32x16_bf16(ah, bl, acc, 0, 0, 0);
            acc = __builtin_amdgcn_mfma_f32_32x32x16_bf16(al, bh, acc, 0, 0, 0);
        }
        if (t + 1 < nt) write_tile(p ^ 1);
        __syncthreads();
        p ^= 1;
    }

    // ---- epilogue: C/D row = (reg&3) + 8*(reg>>2) + 4*(lane>>5), col = lane&31.
    // reg quad q -> 4 consecutive rho = gates i,f,g,o of unit j0 + wr*8 + 2q + hi5.
    const int bloc = lane & 31;
    const int hi5  = lane >> 5;
#pragma unroll
    for (int q = 0; q < 4; ++q) {
        const int uloc = wr * 8 + 2 * q + hi5;
        const int u    = j0 + uloc;
        const float4 bia = *(const float4*)(bperm + 4 * u);
        const float gi = acc[4 * q + 0] + bia.x;
        const float gf = acc[4 * q + 1] + bia.y;
        const float gg = acc[4 * q + 2] + bia.z;
        const float go = acc[4 * q + 3] + bia.w;
        const float iv = 1.0f / (1.0f + expf(-gi));
        const float fv = 1.0f / (1.0f + expf(-gf));
        const float gv = tanhf(gg);
        const float ov = 1.0f / (1.0f + expf(-go));
        float* cp = &cT[(size_t)u * B_ + b0 + bloc];
        const float cn = fv * (*cp) + iv * gv;
        *cp = cn;
        Lh[bloc][uloc] = ov * tanhf(cn);
    }
    __syncthreads();
    {
        const int bl = tid >> 2, part = tid & 3;       // 32 batch x 4 float4-parts
        float4 v;
        v.x = Lh[bl][part * 4 + 0];
        v.y = Lh[bl][part * 4 + 1];
        v.z = Lh[bl][part * 4 + 2];
        v.w = Lh[bl][part * 4 + 3];
        *(float4*)&hout[(size_t)(b0 + bl) * H_ + j0 + part * 4] = v;
    }
}

// ---------------------------------------------------------------------------
// Projection y = h @ Wp^T + bp via bf16x3 MFMA. Rows = plain o (no perm).
// Grid 32 = 8 row-blocks (64 o) x 4 batch-blocks (32); XCD-swizzled likewise.
// ---------------------------------------------------------------------------
__global__ __launch_bounds__(128) void proj_mfma(
    const float* __restrict__ h32,                    // [128 x 1024]
    const ushort* __restrict__ WPh, const ushort* __restrict__ WPl,
    const float* __restrict__ WP32,
    const float* __restrict__ bp,
    float* __restrict__ y,                            // [128 x 512] feedback
    float* __restrict__ outt)                         // d_out + t*O_
{
    __shared__ __align__(16) ushort As[2][2][64][LDA];
    __shared__ __align__(16) ushort Bs[2][2][32][LDA];

    const int tid  = threadIdx.x;
    const int lane = tid & 63;
    const int wr   = tid >> 6;
    const int bid  = blockIdx.x;
    const int o0   = (bid & 7) * 64;      // XCD = bid&7: same-o duplicates colocate
    const int b0   = (bid >> 3) * 32;

    uint4  pA[4];
    float4 pAf[4];
    float4 pB[2];
    const bool afly = (WPh == nullptr);

    auto load_tile = [&](int t) {
        const int k0 = t * 32;
        if (!afly) {
#pragma unroll
            for (int rep = 0; rep < 2; ++rep) {
                const int flat = tid + rep * 128;
                const int r = flat >> 2, c = flat & 3;
                const size_t off = (size_t)(o0 + r) * H_ + k0 + c * 8;
                pA[rep * 2 + 0] = *(const uint4*)(WPh + off);
                pA[rep * 2 + 1] = *(const uint4*)(WPl + off);
            }
        } else {
#pragma unroll
            for (int rep = 0; rep < 4; ++rep) {
                const int flat = tid + rep * 128;
                const int r = flat >> 3, q = flat & 7;
                pAf[rep] = *(const float4*)(WP32 + (size_t)(o0 + r) * H_ + k0 + q * 4);
            }
        }
#pragma unroll
        for (int rep = 0; rep < 2; ++rep) {
            const int flat = tid + rep * 128;
            const int r = flat >> 3, q = flat & 7;
            pB[rep] = *(const float4*)(h32 + (size_t)(b0 + r) * H_ + k0 + q * 4);
        }
    };
    auto write_tile = [&](int p) {
        if (!afly) {
#pragma unroll
            for (int rep = 0; rep < 2; ++rep) {
                const int flat = tid + rep * 128;
                const int r = flat >> 2, c = flat & 3;
                const uint2* h2 = (const uint2*)&pA[rep * 2 + 0];
                const uint2* l2 = (const uint2*)&pA[rep * 2 + 1];
                *(uint2*)&As[p][0][r][c * 8]     = h2[0];
                *(uint2*)&As[p][0][r][c * 8 + 4] = h2[1];
                *(uint2*)&As[p][1][r][c * 8]     = l2[0];
                *(uint2*)&As[p][1][r][c * 8 + 4] = l2[1];
            }
        } else {
#pragma unroll
            for (int rep = 0; rep < 4; ++rep) {
                const int flat = tid + rep * 128;
                const int r = flat >> 3, q = flat & 7;
                uint2 hi, lo; cvt4(pAf[rep], hi, lo);
                *(uint2*)&As[p][0][r][q * 4] = hi;
                *(uint2*)&As[p][1][r][q * 4] = lo;
            }
        }
#pragma unroll
        for (int rep = 0; rep < 2; ++rep) {
            const int flat = tid + rep * 128;
            const int r = flat >> 3, q = flat & 7;
            uint2 hi, lo; cvt4(pB[rep], hi, lo);
            *(uint2*)&Bs[p][0][r][q * 4] = hi;
            *(uint2*)&Bs[p][1][r][q * 4] = lo;
        }
    };

    f32x16 acc;
#pragma unroll
    for (int i = 0; i < 16; ++i) acc[i] = 0.0f;

    const int arow = wr * 32 + (lane & 31);
    const int brow = lane & 31;
    const int koff = (lane >> 5) * 8;

    load_tile(0);
    write_tile(0);
    __syncthreads();

    int p = 0;
    for (int t = 0; t < 32; ++t) {
        if (t + 1 < 32) load_tile(t + 1);
#pragma unroll
        for (int ks = 0; ks < 2; ++ks) {
            const s16x8 ah = rdfrag(&As[p][0][arow][ks * 16 + koff]);
            const s16x8 al = rdfrag(&As[p][1][arow][ks * 16 + koff]);
            const s16x8 bh = rdfrag(&Bs[p][0][brow][ks * 16 + koff]);
            const s16x8 bl = rdfrag(&Bs[p][1][brow][ks * 16 + koff]);
            acc = __builtin_amdgcn_mfma_f32_32x32x16_bf16(ah, bh, acc, 0, 0, 0);
            acc = __builtin_amdgcn_mfma_f32_32x32x16_bf16(ah, bl, acc, 0, 0, 0);
            acc = __builtin_amdgcn_mfma_f32_32x32x16_bf16(al, bh, acc, 0, 0, 0);
        }
        if (t + 1 < 32) write_tile(p ^ 1);
        __syncthreads();
        p ^= 1;
    }

    const int bloc = lane & 31;
    const int hi5  = lane >> 5;
#pragma unroll
    for (int q = 0; q < 4; ++q) {
        const int ob = o0 + wr * 32 + 8 * q + 4 * hi5;  // 4 consecutive o = regs 4q..4q+3
        const float4 bia = *(const float4*)(bp + ob);
        float4 v;
        v.x = acc[4 * q + 0] + bia.x;
        v.y = acc[4 * q + 1] + bia.y;
        v.z = acc[4 * q + 2] + bia.z;
        v.w = acc[4 * q + 3] + bia.w;
        *(float4*)&y[(size_t)(b0 + bloc) * O_ + ob] = v;
        *(float4*)&outt[(size_t)(b0 + bloc) * (T_ * O_) + ob] = v;
    }
}

// Convert fp32 weights -> bf16 hi/lo planes, optional row permutation rho=4j+g.
__global__ void convert_kernel(const float* __restrict__ src,
                               ushort* __restrict__ dh, ushort* __restrict__ dl,
                               int K, int nchunks, int perm)
{
    const int Kq = K >> 2;
    for (int idx = blockIdx.x * 256 + threadIdx.x; idx < nchunks;
         idx += gridDim.x * 256) {
        const int row = idx / Kq;
        const int kq  = idx - row * Kq;
        const size_t srow = perm ? ((size_t)(row & 3) * H_ + (row >> 2)) : (size_t)row;
        const float4 v = *(const float4*)(src + srow * K + kq * 4);
        uint2 hi, lo; cvt4(v, hi, lo);
        *(uint2*)(dh + (size_t)row * K + kq * 4) = hi;
        *(uint2*)(dl + (size_t)row * K + kq * 4) = lo;
    }
}

// Permuted bias sums: bperm[4j+g] = bi[g*H+j] + bh[g*H+j], for enc and dec.
__global__ void prep_bias(const float* __restrict__ bi_e, const float* __restrict__ bh_e,
                          const float* __restrict__ bi_d, const float* __restrict__ bh_d,
                          float* __restrict__ be, float* __restrict__ bd)
{
    const int n = blockIdx.x * 256 + threadIdx.x;
    if (n < 4 * H_) {
        const int src = (n & 3) * H_ + (n >> 2);
        be[n] = bi_e[src] + bh_e[src];
        bd[n] = bi_d[src] + bh_d[src];
    }
}

extern "C" void kernel_launch(void* const* d_in, const int* in_sizes, int n_in,
                              void* d_out, int out_size, void* d_ws, size_t ws_size,
                              hipStream_t stream) {
    const float* x     = (const float*)d_in[0];
    // d_in[1] = tgt_len (compile-time T_ = 128)
    const float* Wih_e = (const float*)d_in[2];
    const float* Whh_e = (const float*)d_in[3];
    const float* bih_e = (const float*)d_in[4];
    const float* bhh_e = (const float*)d_in[5];
    const float* Wih_d = (const float*)d_in[6];
    const float* Whh_d = (const float*)d_in[7];
    const float* bih_d = (const float*)d_in[8];
    const float* bhh_d = (const float*)d_in[9];
    const float* Wp    = (const float*)d_in[10];
    const float* bp    = (const float*)d_in[11];
    float* out = (float*)d_out;
    float* ws  = (float*)d_ws;

    // ---- encoder weight planes live in d_out (dead until decoder writes) ----
    ushort* encXh = (ushort*)d_out;                 // 4096*512
    ushort* encXl = encXh + 2097152;
    ushort* encHh = encXl + 2097152;                // 4096*1024
    ushort* encHl = encHh + 4194304;                // ends at 25.2MB <= 33.5MB

    // ---- ws layout (floats): [cT 131072][h0 131072][y 65536][h1 131072]
    //      [be 4096][bd 4096][planes...] ----
    float* cT = ws;
    float* h0 = ws + 131072;
    float* y  = ws + 262144;
    float* h1 = ws + 327680;
    float* be = ws + 458752;
    float* bd = ws + 462848;
    ushort* planes = (ushort*)(ws + 466944);

    const size_t baseB = 466944ull * 4;
    ushort* decHh = planes;                          // 4096*1024
    ushort* decHl = decHh + 4194304;
    ushort* wpH   = decHl + 4194304;                 // 512*1024
    ushort* wpL   = wpH + 524288;
    ushort* decXh = wpL + 524288;                    // 4096*512
    ushort* decXl = decXh + 2097152;

    const bool haveDecH = ws_size >= baseB + 16777216ull;
    const bool haveWp   = ws_size >= baseB + 16777216ull + 2097152ull;
    const bool haveDecX = ws_size >= baseB + 16777216ull + 2097152ull + 8388608ull;

    // zero cT, h0, y (contiguous prefix)
    hipMemsetAsync(ws, 0, (size_t)327680 * sizeof(float), stream);
    prep_bias<<<16, 256, 0, stream>>>(bih_e, bhh_e, bih_d, bhh_d, be, bd);

    // conversions run every call (d_out/ws re-poisoned by harness each launch)
    convert_kernel<<<2048, 256, 0, stream>>>(Wih_e, encXh, encXl, 512, 4096 * 128, 1);
    convert_kernel<<<2048, 256, 0, stream>>>(Whh_e, encHh, encHl, 1024, 4096 * 256, 1);
    if (haveDecH)
        convert_kernel<<<2048, 256, 0, stream>>>(Whh_d, decHh, decHl, 1024, 4096 * 256, 1);
    if (haveWp)
        convert_kernel<<<2048, 256, 0, stream>>>(Wp, wpH, wpL, 1024, 512 * 256, 0);
    if (haveDecX)
        convert_kernel<<<2048, 256, 0, stream>>>(Wih_d, decXh, decXl, 512, 4096 * 128, 1);

    float* hin  = h0;
    float* hout = h1;

    // ---- encoder: 256 steps, K = 512 (x) + 1024 (h) ----
    for (int t = 0; t < S_; ++t) {
        cell_mfma<<<256, 128, 0, stream>>>(
            x + (size_t)t * I_, S_ * I_,
            encXh, encXl, Wih_e, 16,
            hin, encHh, encHl, Whh_e,
            be, hout, cT);
        float* tmp = hin; hin = hout; hout = tmp;
    }

    // ---- decoder: y feedback (zeros at t=0), per-step projection ----
    for (int t = 0; t < T_; ++t) {
        cell_mfma<<<256, 128, 0, stream>>>(
            y, O_,
            haveDecX ? decXh : nullptr, haveDecX ? decXl : nullptr, Wih_d, 16,
            hin,
            haveDecH ? decHh : nullptr, haveDecH ? decHl : nullptr, Whh_d,
            bd, hout, cT);
        float* tmp = hin; hin = hout; hout = tmp;
        proj_mfma<<<32, 128, 0, stream>>>(
            hin,
            haveWp ? wpH : nullptr, haveWp ? wpL : nullptr, Wp,
            bp, y, out + (size_t)t * O_);
    }
}

// Round 7
// 21152.170 us; speedup vs baseline: 4.1855x; 1.4371x over previous
//
#include <hip/hip_runtime.h>
#include <math.h>

#define B_ 128
#define S_ 256
#define I_ 512
#define H_ 1024
#define O_ 512
#define T_ 128
#define LDA 36            // padded bf16 elems per 32-k LDS row (72B: 8B-aligned, bank-clean)

typedef __attribute__((ext_vector_type(8)))  short s16x8;
typedef __attribute__((ext_vector_type(16))) float f32x16;

__device__ __forceinline__ ushort f2bf(float x) {
    union { float f; uint u; } v; v.f = x;
    return (ushort)((v.u + 0x7FFFu + ((v.u >> 16) & 1u)) >> 16);
}
__device__ __forceinline__ float bf2f(ushort h) {
    union { uint u; float f; } v; v.u = ((uint)h) << 16; return v.f;
}

// split fp32x4 -> bf16 hi/lo planes (compensated; lo stays normal in bf16)
__device__ __forceinline__ void cvt4(float4 v, uint2& hi, uint2& lo) {
    union { ushort h[4]; uint2 u; } H, L;
    ushort a;
    a = f2bf(v.x); H.h[0] = a; L.h[0] = f2bf(v.x - bf2f(a));
    a = f2bf(v.y); H.h[1] = a; L.h[1] = f2bf(v.y - bf2f(a));
    a = f2bf(v.z); H.h[2] = a; L.h[2] = f2bf(v.z - bf2f(a));
    a = f2bf(v.w); H.h[3] = a; L.h[3] = f2bf(v.w - bf2f(a));
    hi = H.u; lo = L.u;
}

__device__ __forceinline__ s16x8 rdfrag(const ushort* p) {
    union { s16x8 v; uint2 u[2]; } r;
    r.u[0] = *(const uint2*)(p);
    r.u[1] = *(const uint2*)(p + 4);
    return r.v;
}

// ---- cross-block sync helpers (agent scope; per-group 64-block barriers) ----
__device__ __forceinline__ void wait_ge(uint* f, uint target) {
    if (threadIdx.x == 0) {
        while (__hip_atomic_load(f, __ATOMIC_RELAXED, __HIP_MEMORY_SCOPE_AGENT) < target)
            __builtin_amdgcn_s_sleep(2);
    }
    __syncthreads();
    __threadfence();   // acquire: invalidate caches before reading published data
}
__device__ __forceinline__ void publish(uint* f) {
    __threadfence();   // each thread: make own global writes device-visible
    __syncthreads();
    if (threadIdx.x == 0)
        __hip_atomic_fetch_add(f, 1u, __ATOMIC_RELEASE, __HIP_MEMORY_SCOPE_AGENT);
}

// ===========================================================================
// PERSISTENT ENCODER: 256 blocks x 128 thr; 256 steps internally.
// Block (rb,bb): units j0..j0+15 (rho rows rho0..rho0+63), batch b0..b0+31.
// Per step: x-phase (16 tiles, independent) -> group-wait h(t) -> h-phase
// (32 tiles) -> epilogue (c private, h(t+1) bf16 planes) -> publish.
// h(t) lives in hb planes buf[t&1]; group = 64 blocks sharing bb.
// ===========================================================================
__global__ __launch_bounds__(128) void enc_persist(
    const float* __restrict__ x,                       // [128][256][512]
    const ushort* __restrict__ WXh, const ushort* __restrict__ WXl,  // [4096][512] perm
    const ushort* __restrict__ WHh, const ushort* __restrict__ WHl,  // [4096][1024] perm
    const float* __restrict__ be,                      // [4096] perm bias
    ushort* __restrict__ hbH, ushort* __restrict__ hbL,              // [2][128][1024]
    float* __restrict__ cT,                            // [1024][128]
    uint* __restrict__ flags)
{
    __shared__ __align__(16) ushort As[2][2][64][LDA];
    __shared__ __align__(16) ushort Bs[2][2][32][LDA];
    __shared__ float Lh[32][20];

    const int tid  = threadIdx.x;
    const int lane = tid & 63;
    const int wr   = tid >> 6;
    const int bid  = blockIdx.x;
    const int rb   = (bid & 7) + 8 * (bid >> 5);
    const int bb   = (bid >> 3) & 3;
    const int j0   = rb * 16;
    const int rho0 = rb * 64;
    const int b0   = bb * 32;
    uint* flg = flags + bb * 16;

    const int arow = wr * 32 + (lane & 31);
    const int brow = lane & 31;
    const int koff = (lane >> 5) * 8;
    const int bloc = lane & 31;
    const int hi5  = lane >> 5;

    uint4  pA[4];
    uint4  pBp[2];
    float4 pBf[2];

    auto stageA = [&](const ushort* Ph, const ushort* Pl, int K, int k0) {
#pragma unroll
        for (int rep = 0; rep < 2; ++rep) {
            const int flat = tid + rep * 128;
            const int r = flat >> 2, cc = flat & 3;
            const size_t off = (size_t)(rho0 + r) * K + k0 + cc * 8;
            pA[rep * 2 + 0] = *(const uint4*)(Ph + off);
            pA[rep * 2 + 1] = *(const uint4*)(Pl + off);
        }
    };
    auto writeA = [&](int p) {
#pragma unroll
        for (int rep = 0; rep < 2; ++rep) {
            const int flat = tid + rep * 128;
            const int r = flat >> 2, cc = flat & 3;
            const uint2* h2 = (const uint2*)&pA[rep * 2 + 0];
            const uint2* l2 = (const uint2*)&pA[rep * 2 + 1];
            *(uint2*)&As[p][0][r][cc * 8]     = h2[0];
            *(uint2*)&As[p][0][r][cc * 8 + 4] = h2[1];
            *(uint2*)&As[p][1][r][cc * 8]     = l2[0];
            *(uint2*)&As[p][1][r][cc * 8 + 4] = l2[1];
        }
    };
    auto stageBf = [&](const float* B32, int ldb, int k0) {
#pragma unroll
        for (int rep = 0; rep < 2; ++rep) {
            const int flat = tid + rep * 128;
            const int r = flat >> 3, q = flat & 7;
            pBf[rep] = *(const float4*)(B32 + (size_t)(b0 + r) * ldb + k0 + q * 4);
        }
    };
    auto writeBf = [&](int p) {
#pragma unroll
        for (int rep = 0; rep < 2; ++rep) {
            const int flat = tid + rep * 128;
            const int r = flat >> 3, q = flat & 7;
            uint2 hi, lo; cvt4(pBf[rep], hi, lo);
            *(uint2*)&Bs[p][0][r][q * 4] = hi;
            *(uint2*)&Bs[p][1][r][q * 4] = lo;
        }
    };
    auto stageBp = [&](const ushort* Bh, const ushort* Bl, int k0) {
        const int r = tid >> 2, q = tid & 3;
        const size_t off = (size_t)(b0 + r) * H_ + k0 + q * 8;
        pBp[0] = *(const uint4*)(Bh + off);
        pBp[1] = *(const uint4*)(Bl + off);
    };
    auto writeBp = [&](int p) {
        const int r = tid >> 2, q = tid & 3;
        const uint2* h2 = (const uint2*)&pBp[0];
        const uint2* l2 = (const uint2*)&pBp[1];
        *(uint2*)&Bs[p][0][r][q * 8]     = h2[0];
        *(uint2*)&Bs[p][0][r][q * 8 + 4] = h2[1];
        *(uint2*)&Bs[p][1][r][q * 8]     = l2[0];
        *(uint2*)&Bs[p][1][r][q * 8 + 4] = l2[1];
    };

    for (int t = 0; t < S_; ++t) {
        f32x16 acc;
#pragma unroll
        for (int i = 0; i < 16; ++i) acc[i] = 0.0f;

        auto inner = [&](int p) {
#pragma unroll
            for (int ks = 0; ks < 2; ++ks) {
                const s16x8 ah = rdfrag(&As[p][0][arow][ks * 16 + koff]);
                const s16x8 al = rdfrag(&As[p][1][arow][ks * 16 + koff]);
                const s16x8 bh = rdfrag(&Bs[p][0][brow][ks * 16 + koff]);
                const s16x8 bl = rdfrag(&Bs[p][1][brow][ks * 16 + koff]);
                acc = __builtin_amdgcn_mfma_f32_32x32x16_bf16(ah, bh, acc, 0, 0, 0);
                acc = __builtin_amdgcn_mfma_f32_32x32x16_bf16(ah, bl, acc, 0, 0, 0);
                acc = __builtin_amdgcn_mfma_f32_32x32x16_bf16(al, bh, acc, 0, 0, 0);
            }
        };

        // ---- x-phase (independent of recurrence; overlaps group stragglers) ----
        const float* xt = x + (size_t)t * I_;
        stageA(WXh, WXl, I_, 0); stageBf(xt, S_ * I_, 0);
        writeA(0); writeBf(0);
        __syncthreads();
        int p = 0;
        for (int tt = 0; tt < 16; ++tt) {
            if (tt + 1 < 16) { stageA(WXh, WXl, I_, (tt + 1) * 32); stageBf(xt, S_ * I_, (tt + 1) * 32); }
            inner(p);
            if (tt + 1 < 16) { writeA(p ^ 1); writeBf(p ^ 1); }
            __syncthreads();
            p ^= 1;
        }

        // ---- wait for h(t) (h(0)=0 pre-zeroed; flag counts publishes) ----
        wait_ge(flg, 64u * (uint)t);

        // ---- h-phase ----
        const ushort* Bh = hbH + (size_t)(t & 1) * (B_ * H_);
        const ushort* Bl = hbL + (size_t)(t & 1) * (B_ * H_);
        stageA(WHh, WHl, H_, 0); stageBp(Bh, Bl, 0);
        writeA(0); writeBp(0);
        __syncthreads();
        p = 0;
        for (int tt = 0; tt < 32; ++tt) {
            if (tt + 1 < 32) { stageA(WHh, WHl, H_, (tt + 1) * 32); stageBp(Bh, Bl, (tt + 1) * 32); }
            inner(p);
            if (tt + 1 < 32) { writeA(p ^ 1); writeBp(p ^ 1); }
            __syncthreads();
            p ^= 1;
        }

        // ---- epilogue: gates -> c (private), h(t+1) -> planes buf[(t+1)&1] ----
#pragma unroll
        for (int q = 0; q < 4; ++q) {
            const int uloc = wr * 8 + 2 * q + hi5;
            const int u    = j0 + uloc;
            const float4 bia = *(const float4*)(be + 4 * u);
            const float gi = acc[4 * q + 0] + bia.x;
            const float gf = acc[4 * q + 1] + bia.y;
            const float gg = acc[4 * q + 2] + bia.z;
            const float go = acc[4 * q + 3] + bia.w;
            const float iv = 1.0f / (1.0f + expf(-gi));
            const float fv = 1.0f / (1.0f + expf(-gf));
            const float gv = tanhf(gg);
            const float ov = 1.0f / (1.0f + expf(-go));
            float* cp = &cT[(size_t)u * B_ + b0 + bloc];
            const float cn = fv * (*cp) + iv * gv;
            *cp = cn;
            Lh[bloc][uloc] = ov * tanhf(cn);
        }
        __syncthreads();
        {
            const int bl = tid >> 2, part = tid & 3;
            float4 v;
            v.x = Lh[bl][part * 4 + 0]; v.y = Lh[bl][part * 4 + 1];
            v.z = Lh[bl][part * 4 + 2]; v.w = Lh[bl][part * 4 + 3];
            uint2 hi, lo; cvt4(v, hi, lo);
            const size_t off = (size_t)((t + 1) & 1) * (B_ * H_) + (size_t)(b0 + bl) * H_ + j0 + part * 4;
            *(uint2*)(hbH + off) = hi;
            *(uint2*)(hbL + off) = lo;
        }
        publish(flg);
    }
}

// ===========================================================================
// PERSISTENT DECODER: 256 blocks x 128 thr; 128 steps + chunked projection.
// Weff folding: gates_t = Weff.s_{t-1} + beff (t>=2); t==1 uses Whh_d (fly).
// h history -> bf16 planes ring (16 slots); every 16 steps blocks project the
// chunk into d_out (2 jobs/block of 32 batch x 64 outs, group-local).
// ===========================================================================
__global__ __launch_bounds__(128) void dec_persist(
    const float* __restrict__ Whh_d,                   // fp32 for step 1 (fly)
    const ushort* __restrict__ WEh, const ushort* __restrict__ WEl,  // Weff planes [4096][1024]
    const ushort* __restrict__ WPh, const ushort* __restrict__ WPl,  // Wp planes [512][1024]
    const float* __restrict__ bd, const float* __restrict__ beff,    // [4096] perm
    const float* __restrict__ bp,                      // [512]
    ushort* __restrict__ hbH, ushort* __restrict__ hbL,
    ushort* __restrict__ histH, ushort* __restrict__ histL,          // [16][128][1024]
    float* __restrict__ cT,
    float* __restrict__ out,                           // [128][128][512]
    uint* __restrict__ flags)                          // dec at +64, proj at +128
{
    __shared__ __align__(16) ushort As[2][2][64][LDA];
    __shared__ __align__(16) ushort Bs[2][2][32][LDA];
    __shared__ float Lh[32][20];

    const int tid  = threadIdx.x;
    const int lane = tid & 63;
    const int wr   = tid >> 6;
    const int bid  = blockIdx.x;
    const int rb   = (bid & 7) + 8 * (bid >> 5);
    const int bb   = (bid >> 3) & 3;
    const int j0   = rb * 16;
    const int rho0 = rb * 64;
    const int b0   = bb * 32;
    uint* flgD = flags + 64 + bb * 16;
    uint* flgP = flags + 128 + bb * 16;

    const int arow = wr * 32 + (lane & 31);
    const int brow = lane & 31;
    const int koff = (lane >> 5) * 8;
    const int bloc = lane & 31;
    const int hi5  = lane >> 5;

    uint4  pA[4];
    float4 pAf[4];
    uint4  pBp[2];

    auto stageA = [&](const ushort* Ph, const ushort* Pl, int rowbase, int K, int k0) {
#pragma unroll
        for (int rep = 0; rep < 2; ++rep) {
            const int flat = tid + rep * 128;
            const int r = flat >> 2, cc = flat & 3;
            const size_t off = (size_t)(rowbase + r) * K + k0 + cc * 8;
            pA[rep * 2 + 0] = *(const uint4*)(Ph + off);
            pA[rep * 2 + 1] = *(const uint4*)(Pl + off);
        }
    };
    auto writeA = [&](int p) {
#pragma unroll
        for (int rep = 0; rep < 2; ++rep) {
            const int flat = tid + rep * 128;
            const int r = flat >> 2, cc = flat & 3;
            const uint2* h2 = (const uint2*)&pA[rep * 2 + 0];
            const uint2* l2 = (const uint2*)&pA[rep * 2 + 1];
            *(uint2*)&As[p][0][r][cc * 8]     = h2[0];
            *(uint2*)&As[p][0][r][cc * 8 + 4] = h2[1];
            *(uint2*)&As[p][1][r][cc * 8]     = l2[0];
            *(uint2*)&As[p][1][r][cc * 8 + 4] = l2[1];
        }
    };
    auto stageAf = [&](const float* W32, int k0) {   // perm rows of Whh_d, K=1024
#pragma unroll
        for (int rep = 0; rep < 4; ++rep) {
            const int flat = tid + rep * 128;
            const int r = flat >> 3, q = flat & 7;
            const int rho = rho0 + r;
            const size_t srow = (size_t)(rho & 3) * H_ + (rho >> 2);
            pAf[rep] = *(const float4*)(W32 + srow * H_ + k0 + q * 4);
        }
    };
    auto writeAf = [&](int p) {
#pragma unroll
        for (int rep = 0; rep < 4; ++rep) {
            const int flat = tid + rep * 128;
            const int r = flat >> 3, q = flat & 7;
            uint2 hi, lo; cvt4(pAf[rep], hi, lo);
            *(uint2*)&As[p][0][r][q * 4] = hi;
            *(uint2*)&As[p][1][r][q * 4] = lo;
        }
    };
    auto stageBp = [&](const ushort* Bh, const ushort* Bl, int rowbase, int k0) {
        const int r = tid >> 2, q = tid & 3;
        const size_t off = (size_t)(rowbase + r) * H_ + k0 + q * 8;
        pBp[0] = *(const uint4*)(Bh + off);
        pBp[1] = *(const uint4*)(Bl + off);
    };
    auto writeBp = [&](int p) {
        const int r = tid >> 2, q = tid & 3;
        const uint2* h2 = (const uint2*)&pBp[0];
        const uint2* l2 = (const uint2*)&pBp[1];
        *(uint2*)&Bs[p][0][r][q * 8]     = h2[0];
        *(uint2*)&Bs[p][0][r][q * 8 + 4] = h2[1];
        *(uint2*)&Bs[p][1][r][q * 8]     = l2[0];
        *(uint2*)&Bs[p][1][r][q * 8 + 4] = l2[1];
    };

    for (int t = 1; t <= T_; ++t) {
        // WAR guard: before overwriting hist slot 0 of a new chunk, the previous
        // chunk's projection (by all group blocks) must be done.
        if (((t - 1) & 15) == 0 && t > 16)
            wait_ge(flgP, 64u * (uint)((t - 1) >> 4));

        f32x16 acc;
#pragma unroll
        for (int i = 0; i < 16; ++i) acc[i] = 0.0f;

        auto inner = [&](int p, f32x16& a) {
#pragma unroll
            for (int ks = 0; ks < 2; ++ks) {
                const s16x8 ah = rdfrag(&As[p][0][arow][ks * 16 + koff]);
                const s16x8 al = rdfrag(&As[p][1][arow][ks * 16 + koff]);
                const s16x8 bh = rdfrag(&Bs[p][0][brow][ks * 16 + koff]);
                const s16x8 bl = rdfrag(&Bs[p][1][brow][ks * 16 + koff]);
                a = __builtin_amdgcn_mfma_f32_32x32x16_bf16(ah, bh, a, 0, 0, 0);
                a = __builtin_amdgcn_mfma_f32_32x32x16_bf16(ah, bl, a, 0, 0, 0);
                a = __builtin_amdgcn_mfma_f32_32x32x16_bf16(al, bh, a, 0, 0, 0);
            }
        };

        wait_ge(flgD, 64u * (uint)(t - 1));    // s_{t-1} ready

        const ushort* Bh = hbH + (size_t)((t - 1) & 1) * (B_ * H_);
        const ushort* Bl = hbL + (size_t)((t - 1) & 1) * (B_ * H_);
        int p = 0;
        if (t == 1) {
            stageAf(Whh_d, 0); stageBp(Bh, Bl, b0, 0);
            writeAf(0); writeBp(0);
            __syncthreads();
            for (int tt = 0; tt < 32; ++tt) {
                if (tt + 1 < 32) { stageAf(Whh_d, (tt + 1) * 32); stageBp(Bh, Bl, b0, (tt + 1) * 32); }
                inner(p, acc);
                if (tt + 1 < 32) { writeAf(p ^ 1); writeBp(p ^ 1); }
                __syncthreads();
                p ^= 1;
            }
        } else {
            stageA(WEh, WEl, rho0, H_, 0); stageBp(Bh, Bl, b0, 0);
            writeA(0); writeBp(0);
            __syncthreads();
            for (int tt = 0; tt < 32; ++tt) {
                if (tt + 1 < 32) { stageA(WEh, WEl, rho0, H_, (tt + 1) * 32); stageBp(Bh, Bl, b0, (tt + 1) * 32); }
                inner(p, acc);
                if (tt + 1 < 32) { writeA(p ^ 1); writeBp(p ^ 1); }
                __syncthreads();
                p ^= 1;
            }
        }

        // ---- epilogue: c private; s_t -> hbuf planes + hist slot ----
        const float* bias = (t == 1) ? bd : beff;
#pragma unroll
        for (int q = 0; q < 4; ++q) {
            const int uloc = wr * 8 + 2 * q + hi5;
            const int u    = j0 + uloc;
            const float4 bia = *(const float4*)(bias + 4 * u);
            const float gi = acc[4 * q + 0] + bia.x;
            const float gf = acc[4 * q + 1] + bia.y;
            const float gg = acc[4 * q + 2] + bia.z;
            const float go = acc[4 * q + 3] + bia.w;
            const float iv = 1.0f / (1.0f + expf(-gi));
            const float fv = 1.0f / (1.0f + expf(-gf));
            const float gv = tanhf(gg);
            const float ov = 1.0f / (1.0f + expf(-go));
            float* cp = &cT[(size_t)u * B_ + b0 + bloc];
            const float cn = fv * (*cp) + iv * gv;
            *cp = cn;
            Lh[bloc][uloc] = ov * tanhf(cn);
        }
        __syncthreads();
        {
            const int bl = tid >> 2, part = tid & 3;
            float4 v;
            v.x = Lh[bl][part * 4 + 0]; v.y = Lh[bl][part * 4 + 1];
            v.z = Lh[bl][part * 4 + 2]; v.w = Lh[bl][part * 4 + 3];
            uint2 hi, lo; cvt4(v, hi, lo);
            const size_t offb = (size_t)(t & 1) * (B_ * H_) + (size_t)(b0 + bl) * H_ + j0 + part * 4;
            *(uint2*)(hbH + offb) = hi;
            *(uint2*)(hbL + offb) = lo;
            const size_t offh = (size_t)((t - 1) & 15) * (B_ * H_) + (size_t)(b0 + bl) * H_ + j0 + part * 4;
            *(uint2*)(histH + offh) = hi;
            *(uint2*)(histL + offh) = lo;
        }
        publish(flgD);

        // ---- chunk projection: t = 16,32,...: project steps t-15..t ----
        if ((t & 15) == 0) {
            wait_ge(flgD, 64u * (uint)t);      // whole group's hist complete
            const int c = (t >> 4) - 1;
            for (int jj = 0; jj < 2; ++jj) {
                const int j  = rb * 2 + jj;
                const int rt = j >> 3;          // hist slot / local t
                const int o0 = (j & 7) * 64;
                f32x16 a2;
#pragma unroll
                for (int i = 0; i < 16; ++i) a2[i] = 0.0f;
                const ushort* PBh = histH + (size_t)rt * (B_ * H_);
                const ushort* PBl = histL + (size_t)rt * (B_ * H_);
                stageA(WPh, WPl, o0, H_, 0); stageBp(PBh, PBl, b0, 0);
                writeA(0); writeBp(0);
                __syncthreads();
                int pp = 0;
                for (int tt = 0; tt < 32; ++tt) {
                    if (tt + 1 < 32) { stageA(WPh, WPl, o0, H_, (tt + 1) * 32); stageBp(PBh, PBl, b0, (tt + 1) * 32); }
                    inner(pp, a2);
                    if (tt + 1 < 32) { writeA(pp ^ 1); writeBp(pp ^ 1); }
                    __syncthreads();
                    pp ^= 1;
                }
                const int tg = 16 * c + rt;     // global output step
#pragma unroll
                for (int q = 0; q < 4; ++q) {
                    const int ob = o0 + wr * 32 + 8 * q + 4 * hi5;
                    const float4 bia = *(const float4*)(bp + ob);
                    float4 v;
                    v.x = a2[4 * q + 0] + bia.x;
                    v.y = a2[4 * q + 1] + bia.y;
                    v.z = a2[4 * q + 2] + bia.z;
                    v.w = a2[4 * q + 3] + bia.w;
                    *(float4*)&out[(size_t)(b0 + bloc) * (T_ * O_) + (size_t)tg * O_ + ob] = v;
                }
            }
            __syncthreads();
            if (tid == 0)
                __hip_atomic_fetch_add(flgP, 1u, __ATOMIC_RELEASE, __HIP_MEMORY_SCOPE_AGENT);
        }
    }
}

// ===========================================================================
// FALLBACK (small ws): round-6 per-step kernels — validated at 30.4 ms.
// ===========================================================================
__global__ __launch_bounds__(128) void cell_mfma(
    const float* __restrict__ xsrc, int ldx,
    const ushort* __restrict__ WXh, const ushort* __restrict__ WXl,
    const float* __restrict__ WX32, int ntx,
    const float* __restrict__ hin,
    const ushort* __restrict__ WHh, const ushort* __restrict__ WHl,
    const float* __restrict__ WH32,
    const float* __restrict__ bperm,
    float* __restrict__ hout,
    float* __restrict__ cT)
{
    __shared__ __align__(16) ushort As[2][2][64][LDA];
    __shared__ __align__(16) ushort Bs[2][2][32][LDA];
    __shared__ float Lh[32][20];

    const int tid  = threadIdx.x;
    const int lane = tid & 63;
    const int wr   = tid >> 6;
    const int bid  = blockIdx.x;
    const int rb   = (bid & 7) + 8 * (bid >> 5);
    const int bb   = (bid >> 3) & 3;
    const int j0   = rb * 16;
    const int rho0 = rb * 64;
    const int b0   = bb * 32;
    const int nt   = ntx + 32;

    uint4  pA[4];
    float4 pAf[4];
    float4 pB[2];
    bool   curAfly = false;

    auto load_tile = [&](int t) {
        const bool xph = (t < ntx);
        const int  k0  = (xph ? t : t - ntx) * 32;
        const ushort* Ph = xph ? WXh : WHh;
        const ushort* Pl = xph ? WXl : WHl;
        const int  K   = xph ? ntx * 32 : H_;
        curAfly = (Ph == nullptr);
        if (!curAfly) {
#pragma unroll
            for (int rep = 0; rep < 2; ++rep) {
                const int flat = tid + rep * 128;
                const int r = flat >> 2, c = flat & 3;
                const size_t off = (size_t)(rho0 + r) * K + k0 + c * 8;
                pA[rep * 2 + 0] = *(const uint4*)(Ph + off);
                pA[rep * 2 + 1] = *(const uint4*)(Pl + off);
            }
        } else {
            const float* W32 = xph ? WX32 : WH32;
#pragma unroll
            for (int rep = 0; rep < 4; ++rep) {
                const int flat = tid + rep * 128;
                const int r = flat >> 3, q = flat & 7;
                const int rho = rho0 + r;
                const size_t srow = (size_t)(rho & 3) * H_ + (rho >> 2);
                pAf[rep] = *(const float4*)(W32 + srow * K + k0 + q * 4);
            }
        }
        const float* Bsrc = xph ? xsrc : hin;
        const int    ldb  = xph ? ldx : H_;
#pragma unroll
        for (int rep = 0; rep < 2; ++rep) {
            const int flat = tid + rep * 128;
            const int r = flat >> 3, q = flat & 7;
            pB[rep] = *(const float4*)(Bsrc + (size_t)(b0 + r) * ldb + k0 + q * 4);
        }
    };

    auto write_tile = [&](int p) {
        if (!curAfly) {
#pragma unroll
            for (int rep = 0; rep < 2; ++rep) {
                const int flat = tid + rep * 128;
                const int r = flat >> 2, c = flat & 3;
                const uint2* h2 = (const uint2*)&pA[rep * 2 + 0];
                const uint2* l2 = (const uint2*)&pA[rep * 2 + 1];
                *(uint2*)&As[p][0][r][c * 8]     = h2[0];
                *(uint2*)&As[p][0][r][c * 8 + 4] = h2[1];
                *(uint2*)&As[p][1][r][c * 8]     = l2[0];
                *(uint2*)&As[p][1][r][c * 8 + 4] = l2[1];
            }
        } else {
#pragma unroll
            for (int rep = 0; rep < 4; ++rep) {
                const int flat = tid + rep * 128;
                const int r = flat >> 3, q = flat & 7;
                uint2 hi, lo; cvt4(pAf[rep], hi, lo);
                *(uint2*)&As[p][0][r][q * 4] = hi;
                *(uint2*)&As[p][1][r][q * 4] = lo;
            }
        }
#pragma unroll
        for (int rep = 0; rep < 2; ++rep) {
            const int flat = tid + rep * 128;
            const int r = flat >> 3, q = flat & 7;
            uint2 hi, lo; cvt4(pB[rep], hi, lo);
            *(uint2*)&Bs[p][0][r][q * 4] = hi;
            *(uint2*)&Bs[p][1][r][q * 4] = lo;
        }
    };

    f32x16 acc;
#pragma unroll
    for (int i = 0; i < 16; ++i) acc[i] = 0.0f;

    const int arow = wr * 32 + (lane & 31);
    const int brow = lane & 31;
    const int koff = (lane >> 5) * 8;

    load_tile(0);
    write_tile(0);
    __syncthreads();

    int p = 0;
    for (int t = 0; t < nt; ++t) {
        if (t + 1 < nt) load_tile(t + 1);
#pragma unroll
        for (int ks = 0; ks < 2; ++ks) {
            const s16x8 ah = rdfrag(&As[p][0][arow][ks * 16 + koff]);
            const s16x8 al = rdfrag(&As[p][1][arow][ks * 16 + koff]);
            const s16x8 bh = rdfrag(&Bs[p][0][brow][ks * 16 + koff]);
            const s16x8 bl = rdfrag(&Bs[p][1][brow][ks * 16 + koff]);
            acc = __builtin_amdgcn_mfma_f32_32x32x16_bf16(ah, bh, acc, 0, 0, 0);
            acc = __builtin_amdgcn_mfma_f32_32x32x16_bf16(ah, bl, acc, 0, 0, 0);
            acc = __builtin_amdgcn_mfma_f32_32x32x16_bf16(al, bh, acc, 0, 0, 0);
        }
        if (t + 1 < nt) write_tile(p ^ 1);
        __syncthreads();
        p ^= 1;
    }

    const int bloc = lane & 31;
    const int hi5  = lane >> 5;
#pragma unroll
    for (int q = 0; q < 4; ++q) {
        const int uloc = wr * 8 + 2 * q + hi5;
        const int u    = j0 + uloc;
        const float4 bia = *(const float4*)(bperm + 4 * u);
        const float gi = acc[4 * q + 0] + bia.x;
        const float gf = acc[4 * q + 1] + bia.y;
        const float gg = acc[4 * q + 2] + bia.z;
        const float go = acc[4 * q + 3] + bia.w;
        const float iv = 1.0f / (1.0f + expf(-gi));
        const float fv = 1.0f / (1.0f + expf(-gf));
        const float gv = tanhf(gg);
        const float ov = 1.0f / (1.0f + expf(-go));
        float* cp = &cT[(size_t)u * B_ + b0 + bloc];
        const float cn = fv * (*cp) + iv * gv;
        *cp = cn;
        Lh[bloc][uloc] = ov * tanhf(cn);
    }
    __syncthreads();
    {
        const int bl = tid >> 2, part = tid & 3;
        float4 v;
        v.x = Lh[bl][part * 4 + 0];
        v.y = Lh[bl][part * 4 + 1];
        v.z = Lh[bl][part * 4 + 2];
        v.w = Lh[bl][part * 4 + 3];
        *(float4*)&hout[(size_t)(b0 + bl) * H_ + j0 + part * 4] = v;
    }
}

__global__ __launch_bounds__(128) void proj_mfma(
    const float* __restrict__ h32,
    const ushort* __restrict__ WPh, const ushort* __restrict__ WPl,
    const float* __restrict__ WP32,
    const float* __restrict__ bp,
    float* __restrict__ y,
    float* __restrict__ outt)
{
    __shared__ __align__(16) ushort As[2][2][64][LDA];
    __shared__ __align__(16) ushort Bs[2][2][32][LDA];

    const int tid  = threadIdx.x;
    const int lane = tid & 63;
    const int wr   = tid >> 6;
    const int bid  = blockIdx.x;
    const int o0   = (bid & 7) * 64;
    const int b0   = (bid >> 3) * 32;

    uint4  pA[4];
    float4 pAf[4];
    float4 pB[2];
    const bool afly = (WPh == nullptr);

    auto load_tile = [&](int t) {
        const int k0 = t * 32;
        if (!afly) {
#pragma unroll
            for (int rep = 0; rep < 2; ++rep) {
                const int flat = tid + rep * 128;
                const int r = flat >> 2, c = flat & 3;
                const size_t off = (size_t)(o0 + r) * H_ + k0 + c * 8;
                pA[rep * 2 + 0] = *(const uint4*)(WPh + off);
                pA[rep * 2 + 1] = *(const uint4*)(WPl + off);
            }
        } else {
#pragma unroll
            for (int rep = 0; rep < 4; ++rep) {
                const int flat = tid + rep * 128;
                const int r = flat >> 3, q = flat & 7;
                pAf[rep] = *(const float4*)(WP32 + (size_t)(o0 + r) * H_ + k0 + q * 4);
            }
        }
#pragma unroll
        for (int rep = 0; rep < 2; ++rep) {
            const int flat = tid + rep * 128;
            const int r = flat >> 3, q = flat & 7;
            pB[rep] = *(const float4*)(h32 + (size_t)(b0 + r) * H_ + k0 + q * 4);
        }
    };
    auto write_tile = [&](int p) {
        if (!afly) {
#pragma unroll
            for (int rep = 0; rep < 2; ++rep) {
                const int flat = tid + rep * 128;
                const int r = flat >> 2, c = flat & 3;
                const uint2* h2 = (const uint2*)&pA[rep * 2 + 0];
                const uint2* l2 = (const uint2*)&pA[rep * 2 + 1];
                *(uint2*)&As[p][0][r][c * 8]     = h2[0];
                *(uint2*)&As[p][0][r][c * 8 + 4] = h2[1];
                *(uint2*)&As[p][1][r][c * 8]     = l2[0];
                *(uint2*)&As[p][1][r][c * 8 + 4] = l2[1];
            }
        } else {
#pragma unroll
            for (int rep = 0; rep < 4; ++rep) {
                const int flat = tid + rep * 128;
                const int r = flat >> 3, q = flat & 7;
                uint2 hi, lo; cvt4(pAf[rep], hi, lo);
                *(uint2*)&As[p][0][r][q * 4] = hi;
                *(uint2*)&As[p][1][r][q * 4] = lo;
            }
        }
#pragma unroll
        for (int rep = 0; rep < 2; ++rep) {
            const int flat = tid + rep * 128;
            const int r = flat >> 3, q = flat & 7;
            uint2 hi, lo; cvt4(pB[rep], hi, lo);
            *(uint2*)&Bs[p][0][r][q * 4] = hi;
            *(uint2*)&Bs[p][1][r][q * 4] = lo;
        }
    };

    f32x16 acc;
#pragma unroll
    for (int i = 0; i < 16; ++i) acc[i] = 0.0f;

    const int arow = wr * 32 + (lane & 31);
    const int brow = lane & 31;
    const int koff = (lane >> 5) * 8;

    load_tile(0);
    write_tile(0);
    __syncthreads();

    int p = 0;
    for (int t = 0; t < 32; ++t) {
        if (t + 1 < 32) load_tile(t + 1);
#pragma unroll
        for (int ks = 0; ks < 2; ++ks) {
            const s16x8 ah = rdfrag(&As[p][0][arow][ks * 16 + koff]);
            const s16x8 al = rdfrag(&As[p][1][arow][ks * 16 + koff]);
            const s16x8 bh = rdfrag(&Bs[p][0][brow][ks * 16 + koff]);
            const s16x8 bl = rdfrag(&Bs[p][1][brow][ks * 16 + koff]);
            acc = __builtin_amdgcn_mfma_f32_32x32x16_bf16(ah, bh, acc, 0, 0, 0);
            acc = __builtin_amdgcn_mfma_f32_32x32x16_bf16(ah, bl, acc, 0, 0, 0);
            acc = __builtin_amdgcn_mfma_f32_32x32x16_bf16(al, bh, acc, 0, 0, 0);
        }
        if (t + 1 < 32) write_tile(p ^ 1);
        __syncthreads();
        p ^= 1;
    }

    const int bloc = lane & 31;
    const int hi5  = lane >> 5;
#pragma unroll
    for (int q = 0; q < 4; ++q) {
        const int ob = o0 + wr * 32 + 8 * q + 4 * hi5;
        const float4 bia = *(const float4*)(bp + ob);
        float4 v;
        v.x = acc[4 * q + 0] + bia.x;
        v.y = acc[4 * q + 1] + bia.y;
        v.z = acc[4 * q + 2] + bia.z;
        v.w = acc[4 * q + 3] + bia.w;
        *(float4*)&y[(size_t)(b0 + bloc) * O_ + ob] = v;
        *(float4*)&outt[(size_t)(b0 + bloc) * (T_ * O_) + ob] = v;
    }
}

// ===========================================================================
// Prep kernels
// ===========================================================================
__global__ void convert_kernel(const float* __restrict__ src,
                               ushort* __restrict__ dh, ushort* __restrict__ dl,
                               int K, int nchunks, int perm)
{
    const int Kq = K >> 2;
    for (int idx = blockIdx.x * 256 + threadIdx.x; idx < nchunks;
         idx += gridDim.x * 256) {
        const int row = idx / Kq;
        const int kq  = idx - row * Kq;
        const size_t srow = perm ? ((size_t)(row & 3) * H_ + (row >> 2)) : (size_t)row;
        const float4 v = *(const float4*)(src + srow * K + kq * 4);
        uint2 hi, lo; cvt4(v, hi, lo);
        *(uint2*)(dh + (size_t)row * K + kq * 4) = hi;
        *(uint2*)(dl + (size_t)row * K + kq * 4) = lo;
    }
}

// be/bd: permuted bias sums; beff = bd + Wih_d(perm row) . bp
__global__ void prep_all(const float* __restrict__ bi_e, const float* __restrict__ bh_e,
                         const float* __restrict__ bi_d, const float* __restrict__ bh_d,
                         const float* __restrict__ Wihd, const float* __restrict__ bp,
                         float* __restrict__ be, float* __restrict__ bd,
                         float* __restrict__ beff)
{
    const int n = blockIdx.x * 256 + threadIdx.x;
    if (n >= 4 * H_) return;
    const int src = (n & 3) * H_ + (n >> 2);
    be[n] = bi_e[src] + bh_e[src];
    const float bdv = bi_d[src] + bh_d[src];
    bd[n] = bdv;
    float s = 0.f;
    const float4* wr4 = reinterpret_cast<const float4*>(Wihd + (size_t)src * I_);
    const float4* bv4 = reinterpret_cast<const float4*>(bp);
#pragma unroll 4
    for (int q = 0; q < I_ / 4; ++q) {
        const float4 w = wr4[q];
        const float4 b = bv4[q];
        s += w.x * b.x + w.y * b.y + w.z * b.z + w.w * b.w;
    }
    beff[n] = bdv + s;
}

// Weff planes: row rho: Weff = Whh_d[src] + Wih_d[src] @ Wp  -> bf16 hi/lo.
// Grid 1024 = 64 rho-tiles x 16 k-tiles; 256 thr; thread 4x4. fp32 VALU GEMM.
__global__ __launch_bounds__(256) void weff_planes(
    const float* __restrict__ Wihd,     // [4096][512]
    const float* __restrict__ Wp,       // [512][1024]
    const float* __restrict__ Whhd,     // [4096][1024]
    ushort* __restrict__ WEh, ushort* __restrict__ WEl)
{
    __shared__ float Asx[32][68];
    __shared__ float Bsx[32][68];
    const int tid = threadIdx.x;
    const int bx = blockIdx.x & 63;
    const int by = blockIdx.x >> 6;
    const int r0 = bx * 64, m0 = by * 64;
    const int tr = tid >> 4, tm = tid & 15;
    float acc[4][4] = {};

    for (int k0 = 0; k0 < I_; k0 += 32) {
        __syncthreads();
#pragma unroll
        for (int rep = 0; rep < 2; ++rep) {
            const int flat = tid + rep * 256;
            const int r = flat >> 3, q = flat & 7;
            const int rho = r0 + r;
            const size_t srow = (size_t)(rho & 3) * H_ + (rho >> 2);
            const float4 v = *(const float4*)(Wihd + srow * I_ + k0 + q * 4);
            Asx[q * 4 + 0][r] = v.x; Asx[q * 4 + 1][r] = v.y;
            Asx[q * 4 + 2][r] = v.z; Asx[q * 4 + 3][r] = v.w;
        }
#pragma unroll
        for (int rep = 0; rep < 2; ++rep) {
            const int flat = tid + rep * 256;
            const int k = flat >> 4, mq = flat & 15;
            const float4 v = *(const float4*)(Wp + (size_t)(k0 + k) * H_ + m0 + mq * 4);
            *(float4*)&Bsx[k][mq * 4] = v;
        }
        __syncthreads();
#pragma unroll
        for (int k = 0; k < 32; ++k) {
            const float4 a4 = *(const float4*)&Asx[k][tr * 4];
            const float4 b4 = *(const float4*)&Bsx[k][tm * 4];
            const float av[4] = {a4.x, a4.y, a4.z, a4.w};
            const float bv[4] = {b4.x, b4.y, b4.z, b4.w};
#pragma unroll
            for (int i = 0; i < 4; ++i)
#pragma unroll
                for (int jx = 0; jx < 4; ++jx)
                    acc[i][jx] = fmaf(av[i], bv[jx], acc[i][jx]);
        }
    }
#pragma unroll
    for (int i = 0; i < 4; ++i) {
        const int rho = r0 + tr * 4 + i;
        const size_t srow = (size_t)(rho & 3) * H_ + (rho >> 2);
        const float4 w = *(const float4*)(Whhd + srow * H_ + m0 + tm * 4);
        float4 o;
        o.x = acc[i][0] + w.x; o.y = acc[i][1] + w.y;
        o.z = acc[i][2] + w.z; o.w = acc[i][3] + w.w;
        uint2 hi, lo; cvt4(o, hi, lo);
        *(uint2*)(WEh + (size_t)rho * H_ + m0 + tm * 4) = hi;
        *(uint2*)(WEl + (size_t)rho * H_ + m0 + tm * 4) = lo;
    }
}

extern "C" void kernel_launch(void* const* d_in, const int* in_sizes, int n_in,
                              void* d_out, int out_size, void* d_ws, size_t ws_size,
                              hipStream_t stream) {
    const float* x     = (const float*)d_in[0];
    const float* Wih_e = (const float*)d_in[2];
    const float* Whh_e = (const float*)d_in[3];
    const float* bih_e = (const float*)d_in[4];
    const float* bhh_e = (const float*)d_in[5];
    const float* Wih_d = (const float*)d_in[6];
    const float* Whh_d = (const float*)d_in[7];
    const float* bih_d = (const float*)d_in[8];
    const float* bhh_d = (const float*)d_in[9];
    const float* Wp    = (const float*)d_in[10];
    const float* bp    = (const float*)d_in[11];
    float* out = (float*)d_out;
    char*  wsb = (char*)d_ws;

    // encoder weight planes live in d_out (dead until decoder proj writes)
    ushort* encXh = (ushort*)d_out;                 // 4096*512
    ushort* encXl = encXh + 2097152;
    ushort* encHh = encXl + 2097152;                // 4096*1024
    ushort* encHl = encHh + 4194304;                // ends 25.2MB <= 33.5MB

    // ---- tier A (persistent) ws layout, byte offsets ----
    float*  cT    = (float*)(wsb + 0);              // 524288 B
    ushort* hbH   = (ushort*)(wsb + 524288);        // 2 x 128x1024
    ushort* hbL   = (ushort*)(wsb + 1048576);
    uint*   flags = (uint*)(wsb + 1572864);         // 4096 B
    float*  be    = (float*)(wsb + 1576960);
    float*  bd    = (float*)(wsb + 1593344);
    float*  beff  = (float*)(wsb + 1609728);
    ushort* wpH   = (ushort*)(wsb + 1626112);       // 512x1024
    ushort* wpL   = (ushort*)(wsb + 2674688);
    ushort* weH   = (ushort*)(wsb + 3723264);       // 4096x1024
    ushort* weL   = (ushort*)(wsb + 12111872);
    ushort* histH = (ushort*)(wsb + 20500480);      // 16x128x1024
    ushort* histL = (ushort*)(wsb + 24694784);
    const size_t TIER_A = 28889088ull;

    if (ws_size >= TIER_A) {
        hipMemsetAsync(wsb, 0, 1576960, stream);    // cT + h planes + flags
        prep_all<<<16, 256, 0, stream>>>(bih_e, bhh_e, bih_d, bhh_d, Wih_d, bp,
                                         be, bd, beff);
        convert_kernel<<<2048, 256, 0, stream>>>(Wih_e, encXh, encXl, 512, 4096 * 128, 1);
        convert_kernel<<<2048, 256, 0, stream>>>(Whh_e, encHh, encHl, 1024, 4096 * 256, 1);
        convert_kernel<<<2048, 256, 0, stream>>>(Wp, wpH, wpL, 1024, 512 * 256, 0);
        weff_planes<<<1024, 256, 0, stream>>>(Wih_d, Wp, Whh_d, weH, weL);

        enc_persist<<<256, 128, 0, stream>>>(x, encXh, encXl, encHh, encHl,
                                             be, hbH, hbL, cT, flags);
        dec_persist<<<256, 128, 0, stream>>>(Whh_d, weH, weL, wpH, wpL,
                                             bd, beff, bp, hbH, hbL,
                                             histH, histL, cT, out, flags);
        return;
    }

    // ---- fallback: round-6 per-step path (validated) ----
    float* ws  = (float*)d_ws;
    float* cT2 = ws;
    float* h0  = ws + 131072;
    float* y   = ws + 262144;
    float* h1  = ws + 327680;
    float* be2 = ws + 458752;
    float* bd2 = ws + 462848;
    float* bef = ws + 466944;
    ushort* planes = (ushort*)(ws + 471040);
    const size_t baseB = 471040ull * 4;
    ushort* decHh = planes;
    ushort* decHl = decHh + 4194304;
    ushort* wpH2  = decHl + 4194304;
    ushort* wpL2  = wpH2 + 524288;
    ushort* decXh = wpL2 + 524288;
    ushort* decXl = decXh + 2097152;
    const bool haveDecH = ws_size >= baseB + 16777216ull;
    const bool haveWp   = ws_size >= baseB + 16777216ull + 2097152ull;
    const bool haveDecX = ws_size >= baseB + 16777216ull + 2097152ull + 8388608ull;

    hipMemsetAsync(ws, 0, (size_t)327680 * sizeof(float), stream);
    prep_all<<<16, 256, 0, stream>>>(bih_e, bhh_e, bih_d, bhh_d, Wih_d, bp,
                                     be2, bd2, bef);
    convert_kernel<<<2048, 256, 0, stream>>>(Wih_e, encXh, encXl, 512, 4096 * 128, 1);
    convert_kernel<<<2048, 256, 0, stream>>>(Whh_e, encHh, encHl, 1024, 4096 * 256, 1);
    if (haveDecH)
        convert_kernel<<<2048, 256, 0, stream>>>(Whh_d, decHh, decHl, 1024, 4096 * 256, 1);
    if (haveWp)
        convert_kernel<<<2048, 256, 0, stream>>>(Wp, wpH2, wpL2, 1024, 512 * 256, 0);
    if (haveDecX)
        convert_kernel<<<2048, 256, 0, stream>>>(Wih_d, decXh, decXl, 512, 4096 * 128, 1);

    float* hin  = h0;
    float* hout = h1;
    for (int t = 0; t < S_; ++t) {
        cell_mfma<<<256, 128, 0, stream>>>(
            x + (size_t)t * I_, S_ * I_, encXh, encXl, Wih_e, 16,
            hin, encHh, encHl, Whh_e, be2, hout, cT2);
        float* tmp = hin; hin = hout; hout = tmp;
    }
    for (int t = 0; t < T_; ++t) {
        cell_mfma<<<256, 128, 0, stream>>>(
            y, O_,
            haveDecX ? decXh : nullptr, haveDecX ? decXl : nullptr, Wih_d, 16,
            hin,
            haveDecH ? decHh : nullptr, haveDecH ? decHl : nullptr, Whh_d,
            bd2, hout, cT2);
        float* tmp = hin; hin = hout; hout = tmp;
        proj_mfma<<<32, 128, 0, stream>>>(
            hin, haveWp ? wpH2 : nullptr, haveWp ? wpL2 : nullptr, Wp,
            bp, y, out + (size_t)t * O_);
    }
}